// Round 7
// baseline (300.144 us; speedup 1.0000x reference)
//
#include <hip/hip_runtime.h>

#define NN 50000     // nodes
#define NE 600000    // directed edges (self loops handled separately)
#define NG 64        // graphs
#define DIM 128      // feature dim (D == H == 128)
#define NCLS 10
#define PS2 16       // pool-edge slices per graph
#define SB 196       // scan blocks = ceil(NN/256)
#define NSLICE 4     // column slices (32 cols = 3.2 MB working set < 4 MB L2/XCD)

typedef unsigned short ushort;
typedef __attribute__((ext_vector_type(8))) short short8;   // 8 bf16 (4 VGPRs)
typedef __attribute__((ext_vector_type(4))) float float4v;  // 4 fp32 acc

__device__ __forceinline__ ushort f2bf(float f) {
    unsigned u = __float_as_uint(f);
    u += 0x7fff + ((u >> 16) & 1);          // RNE
    return (ushort)(u >> 16);
}
__device__ __forceinline__ void acc8(float* a, uint4 v) {
    a[0] += __uint_as_float(v.x << 16); a[1] += __uint_as_float(v.x & 0xffff0000u);
    a[2] += __uint_as_float(v.y << 16); a[3] += __uint_as_float(v.y & 0xffff0000u);
    a[4] += __uint_as_float(v.z << 16); a[5] += __uint_as_float(v.z & 0xffff0000u);
    a[6] += __uint_as_float(v.w << 16); a[7] += __uint_as_float(v.w & 0xffff0000u);
}
__device__ __forceinline__ void acc8w(float* a, uint4 v, float w) {
    a[0] = fmaf(w, __uint_as_float(v.x << 16), a[0]);
    a[1] = fmaf(w, __uint_as_float(v.x & 0xffff0000u), a[1]);
    a[2] = fmaf(w, __uint_as_float(v.y << 16), a[2]);
    a[3] = fmaf(w, __uint_as_float(v.y & 0xffff0000u), a[3]);
    a[4] = fmaf(w, __uint_as_float(v.z << 16), a[4]);
    a[5] = fmaf(w, __uint_as_float(v.z & 0xffff0000u), a[5]);
    a[6] = fmaf(w, __uint_as_float(v.w << 16), a[6]);
    a[7] = fmaf(w, __uint_as_float(v.w & 0xffff0000u), a[7]);
}

// ---------------- init: zero cnt (blocks 0..SB-1) + W->bf16 frag order -----
__global__ void k_init(int* __restrict__ cnt, const float* __restrict__ W1,
                       const float* __restrict__ W2, ushort* __restrict__ Wsw) {
    int b = blockIdx.x, t = threadIdx.x;
    if (b < SB) {
        int i = b * 256 + t;
        if (i < NN) cnt[i] = 0;
    } else {
        int tid = (b - SB) * 256 + t;     // 128 blocks -> 32768 threads
        int layer = tid >> 14;
        int r = tid & 16383;
        int j = r & 7;
        int lane = (r >> 3) & 63;
        int frag = r >> 9;                // nt*4+kc
        int nt = frag >> 2, kc = frag & 3;
        int k = kc * 32 + (lane >> 4) * 8 + j;
        int n = nt * 16 + (lane & 15);
        const float* W = layer ? W2 : W1;
        Wsw[tid] = f2bf(W[k * DIM + n]);
    }
}

// ---------------- degree histogram (2 edges/thread) ----------------
__global__ void k_deg_count(const int* __restrict__ col, int* __restrict__ cnt) {
    int e = (blockIdx.x * blockDim.x + threadIdx.x) * 2;
    if (e < NE) {
        int2 c = *(const int2*)(col + e);
        atomicAdd(&cnt[c.x], 1);
        atomicAdd(&cnt[c.y], 1);
    }
}

// ---------------- per-block partial sums + dinv ----------------
__global__ __launch_bounds__(256) void k_part(const int* __restrict__ cnt,
                                              int* __restrict__ partials,
                                              float* __restrict__ dinv) {
    __shared__ int sm[256];
    int t = threadIdx.x, i = blockIdx.x * 256 + t;
    int c = (i < NN) ? cnt[i] : 0;
    if (i < NN) dinv[i] = rsqrtf(1.0f + (float)c);   // self loop contributes 1
    sm[t] = c;
    __syncthreads();
    for (int s = 128; s > 0; s >>= 1) {
        if (t < s) sm[t] += sm[t + s];
        __syncthreads();
    }
    if (t == 0) partials[blockIdx.x] = sm[0];
}

// 1-block exclusive scan of the SB partials
__global__ __launch_bounds__(256) void k_scanp(int* partials) {
    __shared__ int sm[256];
    int t = threadIdx.x;
    int v = (t < SB) ? partials[t] : 0;
    sm[t] = v;
    __syncthreads();
    for (int off = 1; off < 256; off <<= 1) {
        int u = (t >= off) ? sm[t - off] : 0;
        __syncthreads();
        sm[t] += u;
        __syncthreads();
    }
    if (t < SB) partials[t] = sm[t] - v;   // exclusive prefix
}

// per-block exclusive scan + base -> offsets & cursor (cursor may alias cnt_in)
__global__ __launch_bounds__(256) void k_off(const int* cnt_in, const int* __restrict__ partials,
                                             int* __restrict__ offsets, int* cursor) {
    __shared__ int sm[256];
    int t = threadIdx.x, i = blockIdx.x * 256 + t;
    int v = (i < NN) ? cnt_in[i] : 0;
    sm[t] = v;
    __syncthreads();
    for (int off = 1; off < 256; off <<= 1) {
        int u = (t >= off) ? sm[t - off] : 0;
        __syncthreads();
        sm[t] += u;
        __syncthreads();
    }
    int base = partials[blockIdx.x] + sm[t] - v;
    if (i < NN) { offsets[i] = base; cursor[i] = base; }
    if (i == NN) offsets[NN] = base;
}

// ---------------- CSR fill (2 edges/thread): packed (src, dinv[dst]) -------
__global__ void k_csr_fill(const int* __restrict__ row, const int* __restrict__ col,
                           const float* __restrict__ dinv,
                           int* __restrict__ cursor, int2* __restrict__ edata) {
    int e = (blockIdx.x * blockDim.x + threadIdx.x) * 2;
    if (e < NE) {
        int2 r = *(const int2*)(row + e);
        int2 c = *(const int2*)(col + e);
        int p0 = atomicAdd(&cursor[c.x], 1);
        edata[p0] = make_int2(r.x, __float_as_int(dinv[c.x]));
        int p1 = atomicAdd(&cursor[c.y], 1);
        edata[p1] = make_int2(r.y, __float_as_int(dinv[c.y]));
    }
}

// ---------------- MFMA GEMM: Hs[n,c] = dinv[n] * sum_k A[n,k] W[k,c] -------
template <bool IN_BF16>
__global__ __launch_bounds__(256) void k_gemm_mfma(const void* __restrict__ Ain,
                                                   const ushort* __restrict__ Wsw,
                                                   const float* __restrict__ dinv,
                                                   ushort* __restrict__ Hs) {
    const int t = threadIdx.x;
    const int wave = t >> 6, lane = t & 63;
    const int m = lane & 15, quad = lane >> 4;
    const int row0 = blockIdx.x * 64 + wave * 16;

    short8 bfrag[8][4];
#pragma unroll
    for (int nt = 0; nt < 8; ++nt)
#pragma unroll
        for (int kc = 0; kc < 4; ++kc)
            bfrag[nt][kc] = *(const short8*)(Wsw + ((nt * 4 + kc) * 64 + lane) * 8);

    float4v acc[8];
#pragma unroll
    for (int nt = 0; nt < 8; ++nt) acc[nt] = (float4v){0.f, 0.f, 0.f, 0.f};

    const int row = row0 + m;
    const int rclamp = row < NN ? row : NN - 1;

#pragma unroll
    for (int kc = 0; kc < 4; ++kc) {
        short8 a;
        if (IN_BF16) {
            a = *(const short8*)((const ushort*)Ain + (size_t)rclamp * DIM + kc * 32 + quad * 8);
        } else {
            const float* ap = (const float*)Ain + (size_t)rclamp * DIM + kc * 32 + quad * 8;
            float4 v0 = *(const float4*)ap;
            float4 v1 = *(const float4*)(ap + 4);
            union { short8 v; ushort u[8]; } tmp;
            tmp.u[0] = f2bf(v0.x); tmp.u[1] = f2bf(v0.y);
            tmp.u[2] = f2bf(v0.z); tmp.u[3] = f2bf(v0.w);
            tmp.u[4] = f2bf(v1.x); tmp.u[5] = f2bf(v1.y);
            tmp.u[6] = f2bf(v1.z); tmp.u[7] = f2bf(v1.w);
            a = tmp.v;
        }
#pragma unroll
        for (int nt = 0; nt < 8; ++nt)
            acc[nt] = __builtin_amdgcn_mfma_f32_16x16x32_bf16(a, bfrag[nt][kc], acc[nt], 0, 0, 0);
    }

    // C/D: col = nt*16 + (lane&15), row = row0 + quad*4 + reg
#pragma unroll
    for (int reg = 0; reg < 4; ++reg) {
        int r = row0 + quad * 4 + reg;
        if (r < NN) {
            float d = dinv[r];
#pragma unroll
            for (int nt = 0; nt < 8; ++nt)
                Hs[(size_t)r * DIM + nt * 16 + m] = f2bf(d * acc[nt][reg]);
        }
    }
}

// ---------------- column-sliced CSR gather (layer 1) -----------------------
// out[n, slice] = relu(dinv[n]*(Hs[n,slice] + sum_r Hs[r,slice]) + b[slice])
// grid (782, NSLICE): blockIdx.x fastest => slice-major execution, 3.2 MB
// slice working set resident in each XCD's L2. 4 lanes/node, uint4/lane.
__global__ __launch_bounds__(256) void k_gather_bf(const int* __restrict__ offsets,
                                                   const int2* __restrict__ edata,
                                                   const float* __restrict__ dinv,
                                                   const float* __restrict__ bias,
                                                   const ushort* __restrict__ Hs,
                                                   ushort* __restrict__ out) {
    const int t = threadIdx.x;
    const int node = blockIdx.x * 64 + (t >> 2);
    if (node >= NN) return;
    const int colbase = blockIdx.y * 32 + (t & 3) * 8;
    int beg = offsets[node], end = offsets[node + 1];

    float a[8] = {0.f, 0.f, 0.f, 0.f, 0.f, 0.f, 0.f, 0.f};
    acc8(a, *(const uint4*)(Hs + (size_t)node * DIM + colbase));   // self loop

    int e = beg;
    for (; e + 8 <= end; e += 8) {
        int r0 = edata[e].x,     r1 = edata[e + 1].x, r2 = edata[e + 2].x, r3 = edata[e + 3].x;
        int r4 = edata[e + 4].x, r5 = edata[e + 5].x, r6 = edata[e + 6].x, r7 = edata[e + 7].x;
        uint4 v0 = *(const uint4*)(Hs + (size_t)r0 * DIM + colbase);
        uint4 v1 = *(const uint4*)(Hs + (size_t)r1 * DIM + colbase);
        uint4 v2 = *(const uint4*)(Hs + (size_t)r2 * DIM + colbase);
        uint4 v3 = *(const uint4*)(Hs + (size_t)r3 * DIM + colbase);
        uint4 v4 = *(const uint4*)(Hs + (size_t)r4 * DIM + colbase);
        uint4 v5 = *(const uint4*)(Hs + (size_t)r5 * DIM + colbase);
        uint4 v6 = *(const uint4*)(Hs + (size_t)r6 * DIM + colbase);
        uint4 v7 = *(const uint4*)(Hs + (size_t)r7 * DIM + colbase);
        acc8(a, v0); acc8(a, v1); acc8(a, v2); acc8(a, v3);
        acc8(a, v4); acc8(a, v5); acc8(a, v6); acc8(a, v7);
    }
    for (; e < end; ++e)
        acc8(a, *(const uint4*)(Hs + (size_t)edata[e].x * DIM + colbase));

    float d = dinv[node];
    float4 b0 = *(const float4*)(bias + colbase);
    float4 b1 = *(const float4*)(bias + colbase + 4);
    a[0] = fmaxf(fmaf(a[0], d, b0.x), 0.f); a[1] = fmaxf(fmaf(a[1], d, b0.y), 0.f);
    a[2] = fmaxf(fmaf(a[2], d, b0.z), 0.f); a[3] = fmaxf(fmaf(a[3], d, b0.w), 0.f);
    a[4] = fmaxf(fmaf(a[4], d, b1.x), 0.f); a[5] = fmaxf(fmaf(a[5], d, b1.y), 0.f);
    a[6] = fmaxf(fmaf(a[6], d, b1.z), 0.f); a[7] = fmaxf(fmaf(a[7], d, b1.w), 0.f);
    uint4 o;
    o.x = (unsigned)f2bf(a[0]) | ((unsigned)f2bf(a[1]) << 16);
    o.y = (unsigned)f2bf(a[2]) | ((unsigned)f2bf(a[3]) << 16);
    o.z = (unsigned)f2bf(a[4]) | ((unsigned)f2bf(a[5]) << 16);
    o.w = (unsigned)f2bf(a[6]) | ((unsigned)f2bf(a[7]) << 16);
    *(uint4*)(out + (size_t)node * DIM + colbase) = o;
}

// ---------------- column-sliced fused layer-2 aggregation + pooling --------
// partial[g*PS2+s, slice] = sum over slice-s chunk of graph-g edges/nodes.
// grid (NG*PS2, NSLICE), slice-major. 4 lanes/row, 64 rows in flight/block.
__global__ __launch_bounds__(256) void k_pool_edge(const int* __restrict__ offsets,
                                                   const int2* __restrict__ edata,
                                                   const float* __restrict__ dinv,
                                                   const int* __restrict__ batch,
                                                   const ushort* __restrict__ Hs,
                                                   float* __restrict__ partial) {
    const int g = blockIdx.x / PS2, s = blockIdx.x % PS2;
    const int t = threadIdx.x;
    int start;
    { int a = 0, b = NN; while (a < b) { int m = (a + b) >> 1; if (batch[m] < g) a = m + 1; else b = m; } start = a; }
    int end;
    { int a = 0, b = NN; while (a < b) { int m = (a + b) >> 1; if (batch[m] < g + 1) a = m + 1; else b = m; } end = a; }

    const int lane = t & 3, item = t >> 2;   // 64 rows in flight
    const int colbase = blockIdx.y * 32 + lane * 8;
    float a[8] = {0.f, 0.f, 0.f, 0.f, 0.f, 0.f, 0.f, 0.f};

    // edge term: slice of this graph's contiguous CSR range
    {
        const int elo = offsets[start], ehi = offsets[end];
        const int ecnt = ehi - elo;
        const int chunk = (ecnt + PS2 - 1) / PS2;
        const int lo = elo + s * chunk;
        const int hi = min(lo + chunk, ehi);
        int e = lo + item;
        for (; e + 64 < hi; e += 128) {      // 2 rows in flight per thread
            int2 e0 = edata[e], e1 = edata[e + 64];
            uint4 v0 = *(const uint4*)(Hs + (size_t)e0.x * DIM + colbase);
            uint4 v1 = *(const uint4*)(Hs + (size_t)e1.x * DIM + colbase);
            acc8w(a, v0, __int_as_float(e0.y));
            acc8w(a, v1, __int_as_float(e1.y));
        }
        for (; e < hi; e += 64) {
            int2 ed = edata[e];
            acc8w(a, *(const uint4*)(Hs + (size_t)ed.x * DIM + colbase), __int_as_float(ed.y));
        }
    }
    // self term: slice of this graph's node range (sequential reads)
    {
        const int ncnt = end - start;
        const int chunk = (ncnt + PS2 - 1) / PS2;
        const int lo = start + s * chunk;
        const int hi = min(lo + chunk, end);
        for (int n = lo + item; n < hi; n += 64)
            acc8w(a, *(const uint4*)(Hs + (size_t)n * DIM + colbase), dinv[n]);
    }

    __shared__ float sm[64 * 33];            // pad 33 to break bank aliasing
#pragma unroll
    for (int j = 0; j < 8; ++j) sm[item * 33 + lane * 8 + j] = a[j];
    __syncthreads();
    if (t < 32) {
        float sum = 0.f;
#pragma unroll 8
        for (int r = 0; r < 64; ++r) sum += sm[r * 33 + t];
        partial[(size_t)blockIdx.x * DIM + blockIdx.y * 32 + t] = sum;
    }
}

// ---------------- reduce slices, /cnt, + b2, linear head ----------------
__global__ __launch_bounds__(128) void k_logits(const float* __restrict__ partial,
                                                const float* __restrict__ b2,
                                                const float* __restrict__ Wlin,
                                                const float* __restrict__ blin,
                                                const int* __restrict__ batch,
                                                float* __restrict__ out) {
    const int g = blockIdx.x;
    const int t = threadIdx.x;
    int start;
    { int a = 0, b = NN; while (a < b) { int m = (a + b) >> 1; if (batch[m] < g) a = m + 1; else b = m; } start = a; }
    int end;
    { int a = 0, b = NN; while (a < b) { int m = (a + b) >> 1; if (batch[m] < g + 1) a = m + 1; else b = m; } end = a; }
    const int cnt = end - start;

    __shared__ float pooled[DIM];
    float sum = 0.f;
#pragma unroll
    for (int s = 0; s < PS2; ++s) sum += partial[(size_t)(g * PS2 + s) * DIM + t];
    pooled[t] = (cnt > 0) ? (sum / (float)cnt + b2[t]) : 0.f;
    __syncthreads();
    if (t < NCLS) {
        float s = blin[t];
        for (int k = 0; k < DIM; ++k) s += pooled[k] * Wlin[k * NCLS + t];
        out[g * NCLS + t] = s;
    }
}

extern "C" void kernel_launch(void* const* d_in, const int* in_sizes, int n_in,
                              void* d_out, int out_size, void* d_ws, size_t ws_size,
                              hipStream_t stream) {
    const float* x    = (const float*)d_in[0];
    const float* W1   = (const float*)d_in[1];
    const float* b1   = (const float*)d_in[2];
    const float* W2   = (const float*)d_in[3];
    const float* b2   = (const float*)d_in[4];
    const float* Wlin = (const float*)d_in[5];
    const float* blin = (const float*)d_in[6];
    const int* eidx   = (const int*)d_in[7];   // [2, E] flat: rows then cols
    const int* batch  = (const int*)d_in[8];
    float* out = (float*)d_out;

    char* ws = (char*)d_ws;
    float*  dinv     = (float*)(ws + 0);                   // 200000 B
    int*    cnt      = (int*)(ws + 200000);                // 200000 B (becomes cursor)
    int*    offs     = (int*)(ws + 400000);                // 200016 B (NN+1)
    int2*   edata    = (int2*)(ws + 600016);               // 4800000 B packed (src, dnorm)
    int*    partials = (int*)(ws + 5400016);               // 1024 B
    ushort* Wsw      = (ushort*)(ws + 5401040);            // 65536 B (2 layers)
    ushort* bufA     = (ushort*)(ws + 5466576);            // 12.8 MB bf16 [NN][128]
    ushort* bufB     = (ushort*)(ws + 5466576 + (size_t)NN * DIM * 2);
    float*  poolpt   = (float*)(ws + 5466576 + 2 * (size_t)NN * DIM * 2);  // 512 KB

    const int* erow = eidx;
    const int* ecol = eidx + NE;

    // ---- CSR build + norms + weight prep ----
    k_init<<<SB + 128, 256, 0, stream>>>(cnt, W1, W2, Wsw);
    k_deg_count<<<(NE / 2 + 255) / 256, 256, 0, stream>>>(ecol, cnt);
    k_part<<<SB, 256, 0, stream>>>(cnt, partials, dinv);
    k_scanp<<<1, 256, 0, stream>>>(partials);
    k_off<<<SB, 256, 0, stream>>>(cnt, partials, offs, cnt /*cursor*/);
    k_csr_fill<<<(NE / 2 + 255) / 256, 256, 0, stream>>>(erow, ecol, dinv, cnt, edata);

    const int gemm_grid = (NN + 63) / 64;            // 782
    const dim3 gather_grid((NN + 63) / 64, NSLICE);  // slice-major (x fastest)
    const dim3 pool_grid(NG * PS2, NSLICE);

    // layer 1: Hs1 = dinv*(x @ W1) ; A2 = relu(dinv*(self+nbrs) + b1)
    k_gemm_mfma<false><<<gemm_grid, 256, 0, stream>>>(x, Wsw, dinv, bufA);
    k_gather_bf<<<gather_grid, 256, 0, stream>>>(offs, edata, dinv, b1, bufA, bufB);

    // layer 2: Hs2 = dinv*(A2 @ W2) ; fused aggregation+pool (no per-node agg2)
    k_gemm_mfma<true><<<gemm_grid, 256, 0, stream>>>(bufB, Wsw + 16384, dinv, bufA);
    k_pool_edge<<<pool_grid, 256, 0, stream>>>(offs, edata, dinv, batch, bufA, poolpt);

    // reduce + b2 + linear head
    k_logits<<<NG, 128, 0, stream>>>(poolpt, b2, Wlin, blin, batch, out);
}